// Round 6
// baseline (126.879 us; speedup 1.0000x reference)
//
#include <hip/hip_runtime.h>
#include <hip/hip_bf16.h>

// AvgPool2d 2x2 stride 2, no padding.
// x: [32, 256, 128, 128] f32 -> out: [32, 256, 64, 64] f32.
//
// Mapping: one thread per float2 of output (2 adjacent output columns).
// Each thread loads one float4 from input row 2*oh and one from row 2*oh+1
// (contiguous 16B/lane), computes two averages, stores one float2.
//
// Config history: NT loads+stores, unroll 4 (R3, 130.6us); block-contiguous
// windows (R5, 113.9us = 5.89 TB/s). This round's single knob: GRID 4096->1024,
// ITERS 16->64 — halves concurrent block-streams (2048->1024) for DRAM page
// locality; latency hiding still ample (4 blocks/CU x 4 waves x 8KB in flight
// per wave >> ~21KB/CU needed).
//
// n_units = 16,777,216 = GRID(1024) * BLOCK(256) * ITERS(64), exact.

typedef float f32x4 __attribute__((ext_vector_type(4)));
typedef float f32x2 __attribute__((ext_vector_type(2)));

#define IN_W   128
#define IN_HW  (128 * 128)

#define GRID   1024
#define BLOCK  256
#define ITERS  64

__global__ __launch_bounds__(BLOCK) void avgpool2x2_kernel(
    const float* __restrict__ in, float* __restrict__ out) {
    const int base = blockIdx.x * (BLOCK * ITERS) + threadIdx.x;

#pragma unroll 4
    for (int it = 0; it < ITERS; ++it) {
        int u = base + it * BLOCK;

        int ow2 = u & 31;            // which float2 within the 64-wide output row
        int rest = u >> 5;
        int oh = rest & 63;
        int img = rest >> 6;         // fused (n, c) index, 0..8191

        const float* src = in + (size_t)img * IN_HW + (size_t)(2 * oh) * IN_W + ow2 * 4;
        f32x4 a = __builtin_nontemporal_load(reinterpret_cast<const f32x4*>(src));
        f32x4 b = __builtin_nontemporal_load(reinterpret_cast<const f32x4*>(src + IN_W));

        f32x2 r;
        r.x = (a.x + a.y + b.x + b.y) * 0.25f;
        r.y = (a.z + a.w + b.z + b.w) * 0.25f;
        __builtin_nontemporal_store(r, reinterpret_cast<f32x2*>(out + (size_t)u * 2));
    }
}

extern "C" void kernel_launch(void* const* d_in, const int* in_sizes, int n_in,
                              void* d_out, int out_size, void* d_ws, size_t ws_size,
                              hipStream_t stream) {
    const float* x = (const float*)d_in[0];
    float* out = (float*)d_out;

    // out_size = 32*256*64*64 = 33,554,432 -> 16,777,216 float2 units,
    // exactly GRID*BLOCK*ITERS.
    avgpool2x2_kernel<<<GRID, BLOCK, 0, stream>>>(x, out);
}

// Round 7
// 114.026 us; speedup vs baseline: 1.1127x; 1.1127x over previous
//
#include <hip/hip_runtime.h>
#include <hip/hip_bf16.h>

// AvgPool2d 2x2 stride 2, no padding.
// x: [32, 256, 128, 128] f32 -> out: [32, 256, 64, 64] f32.
//
// Mapping: one thread per float2 of output (2 adjacent output columns).
// Each thread loads one float4 from input row 2*oh and one from row 2*oh+1
// (contiguous 16B/lane), computes two averages, stores one float2.
//
// BEST CONFIG (R5, 113.9us = 5.89 TB/s effective, ~97% in-kernel of the
// 6.29 TB/s copy ceiling): NT loads+stores, unroll 4, block-contiguous
// 4096-unit windows, GRID=4096 (8 blocks/CU resident, 2048 streams).
// Measured worse: scattered grid-stride (R3: 130.6), unroll 8 (R4: 143.0),
// GRID=1024/ITERS=64 (R6: 126.9 — too little DRAM concurrency).
//
// n_units = 16,777,216 = GRID(4096) * BLOCK(256) * ITERS(16), exact.

typedef float f32x4 __attribute__((ext_vector_type(4)));
typedef float f32x2 __attribute__((ext_vector_type(2)));

#define IN_W   128
#define IN_HW  (128 * 128)

#define GRID   4096
#define BLOCK  256
#define ITERS  16

__global__ __launch_bounds__(BLOCK) void avgpool2x2_kernel(
    const float* __restrict__ in, float* __restrict__ out) {
    const int base = blockIdx.x * (BLOCK * ITERS) + threadIdx.x;

#pragma unroll 4
    for (int it = 0; it < ITERS; ++it) {
        int u = base + it * BLOCK;

        int ow2 = u & 31;            // which float2 within the 64-wide output row
        int rest = u >> 5;
        int oh = rest & 63;
        int img = rest >> 6;         // fused (n, c) index, 0..8191

        const float* src = in + (size_t)img * IN_HW + (size_t)(2 * oh) * IN_W + ow2 * 4;
        f32x4 a = __builtin_nontemporal_load(reinterpret_cast<const f32x4*>(src));
        f32x4 b = __builtin_nontemporal_load(reinterpret_cast<const f32x4*>(src + IN_W));

        f32x2 r;
        r.x = (a.x + a.y + b.x + b.y) * 0.25f;
        r.y = (a.z + a.w + b.z + b.w) * 0.25f;
        __builtin_nontemporal_store(r, reinterpret_cast<f32x2*>(out + (size_t)u * 2));
    }
}

extern "C" void kernel_launch(void* const* d_in, const int* in_sizes, int n_in,
                              void* d_out, int out_size, void* d_ws, size_t ws_size,
                              hipStream_t stream) {
    const float* x = (const float*)d_in[0];
    float* out = (float*)d_out;

    // out_size = 32*256*64*64 = 33,554,432 -> 16,777,216 float2 units,
    // exactly GRID*BLOCK*ITERS.
    avgpool2x2_kernel<<<GRID, BLOCK, 0, stream>>>(x, out);
}